// Round 1
// 1042.699 us; speedup vs baseline: 1.0875x; 1.0875x over previous
//
#include <hip/hip_runtime.h>
#include <hip/hip_bf16.h>

#define Bn 4
#define Sn 1024
#define Dn 1024
#define Hn 16
#define DHn 64
#define BSn 4096
#define D2n 2048

typedef __attribute__((ext_vector_type(8))) short short8;
typedef __attribute__((ext_vector_type(8))) __bf16 bf16x8;
typedef __attribute__((ext_vector_type(4))) float floatx4;

static __device__ __forceinline__ unsigned short f2bf(float f) {
  union { float f; unsigned int u; } v; v.f = f;
  unsigned int u = v.u;
  u += 0x7fffu + ((u >> 16) & 1u);
  return (unsigned short)(u >> 16);
}

static __device__ __forceinline__ float bf2f(unsigned short s) {
  union { unsigned int u; float f; } v;
  v.u = ((unsigned int)s) << 16;
  return v.f;
}

static __device__ __forceinline__ floatx4 mfma16(short8 a, short8 b, floatx4 c) {
  return __builtin_amdgcn_mfma_f32_16x16x32_bf16(
      __builtin_bit_cast(bf16x8, a), __builtin_bit_cast(bf16x8, b), c, 0, 0, 0);
}

// ---------------- fp32 -> bf16 convert ----------------
__global__ void k_cvt_bf16(const float* __restrict__ in,
                           unsigned short* __restrict__ out, int n) {
  int i = (blockIdx.x * 256 + threadIdx.x) * 4;
  if (i >= n) return;
  float4 v = *(const float4*)(in + i);
  ushort4 o;
  o.x = f2bf(v.x); o.y = f2bf(v.y); o.z = f2bf(v.z); o.w = f2bf(v.w);
  *(ushort4*)(out + i) = o;
}

// ---------------- LDS-staged MFMA core (m97 structure) -----------------------
// Block = 256 threads (4 waves), tile 128(M) x 128(N), BK=64.
// Wave w owns the 64x64 sub-tile at (w>>1, w&1). A is [M][K] bf16 row-major,
// W is [N][K] bf16 row-major (computes A @ W^T). Both strides == K.
// LDS layout: As/Bs [128 rows][64 k] bf16, with per-row XOR chunk swizzle:
//   LDS[row][c] (c = 16B chunk, 0..7) holds global chunk (c ^ (row&7)).
// Staging uses global_load_lds width=16 with the swizzle applied on the
// per-lane GLOBAL source address (LDS dest stays linear, rule m173/m104).
// Accumulation order over k is identical to the direct-load version
// (k0 ascending, ks ascending) -> bit-identical results.
static __device__ __forceinline__ void gemm_core_lds(
    const unsigned short* __restrict__ A,   // pre-offset: + m0*K
    const unsigned short* __restrict__ W,   // pre-offset: + n0*K
    int K, floatx4 acc[4][4], int tid,
    unsigned short* As, unsigned short* Bs) {
  const int lane = tid & 63, w = tid >> 6;
  const int r = lane & 15, qd = lane >> 4;
  const int srow = lane >> 3;                 // row-within-8-row group, 0..7
  const int scg = (lane & 7) ^ srow;          // swizzled global 16B-chunk idx
  // per-lane global base: rows w*32 + i*8 + srow, chunk scg
  const unsigned short* ag = A + (size_t)(w * 32 + srow) * K + scg * 8;
  const unsigned short* bg = W + (size_t)(w * 32 + srow) * K + scg * 8;
  const int aB = (w >> 1) * 64, bB = (w & 1) * 64;

  for (int k0 = 0; k0 < K; k0 += 64) {
#pragma unroll
    for (int i = 0; i < 4; ++i) {
      // instruction idx = w*4+i covers rows [ (w*4+i)*8, +8 ), 1 KiB of LDS
      __builtin_amdgcn_global_load_lds(
          (const __attribute__((address_space(1))) void*)(ag + (size_t)i * 8 * K + k0),
          (__attribute__((address_space(3))) void*)(As + (w * 4 + i) * 512),
          16, 0, 0);
      __builtin_amdgcn_global_load_lds(
          (const __attribute__((address_space(1))) void*)(bg + (size_t)i * 8 * K + k0),
          (__attribute__((address_space(3))) void*)(Bs + (w * 4 + i) * 512),
          16, 0, 0);
    }
    __syncthreads();   // compiler emits vmcnt(0) drain before s_barrier
#pragma unroll
    for (int ks = 0; ks < 2; ++ks) {
      short8 a[4], b[4];
#pragma unroll
      for (int i = 0; i < 4; ++i)
        a[i] = *(const short8*)&As[(size_t)(aB + i * 16 + r) * 64 +
                                   (((ks * 4 + qd) ^ (r & 7)) * 8)];
#pragma unroll
      for (int j = 0; j < 4; ++j)
        b[j] = *(const short8*)&Bs[(size_t)(bB + j * 16 + r) * 64 +
                                   (((ks * 4 + qd) ^ (r & 7)) * 8)];
#pragma unroll
      for (int i = 0; i < 4; ++i)
#pragma unroll
        for (int j = 0; j < 4; ++j)
          acc[i][j] = mfma16(a[i], b[j], acc[i][j]);
    }
    __syncthreads();
  }
}

// ---------------- proj GEMM with bf16 output (q/k projections) ----------------
__global__ __launch_bounds__(256) void k_gemm_bf16out(
    const unsigned short* __restrict__ A, const unsigned short* __restrict__ W,
    const float* __restrict__ bias, unsigned short* __restrict__ Cout,
    int M, int N, int K) {
  __shared__ __align__(16) unsigned short As[128 * 64];
  __shared__ __align__(16) unsigned short Bs[128 * 64];
  const int lane = threadIdx.x & 63;
  const int m0 = blockIdx.y * 128;
  const int n0 = blockIdx.x * 128;
  floatx4 acc[4][4] = {};
  gemm_core_lds(A + (size_t)m0 * K, W + (size_t)n0 * K, K, acc, threadIdx.x, As, Bs);
  const int w = threadIdx.x >> 6;
  const int wm = m0 + (w >> 1) * 64, wn = n0 + (w & 1) * 64;
  const int r = lane & 15, qd = lane >> 4;
#pragma unroll
  for (int i = 0; i < 4; ++i)
#pragma unroll
    for (int j = 0; j < 4; ++j) {
      int col = wn + j * 16 + r;
      float bv = bias[col];
#pragma unroll
      for (int rg = 0; rg < 4; ++rg) {
        int row = wm + i * 16 + qd * 4 + rg;
        Cout[(size_t)row * N + col] = f2bf(acc[i][j][rg] + bv);
      }
    }
}

// ---------------- v projection, written transposed: vT[b][h][dh][s] bf16 -----
__global__ __launch_bounds__(256) void k_gemm_vT(
    const unsigned short* __restrict__ A, const unsigned short* __restrict__ W,
    const float* __restrict__ bias, unsigned short* __restrict__ vT) {
  __shared__ __align__(16) unsigned short As[128 * 64];
  __shared__ __align__(16) unsigned short Bs[128 * 64];
  const int lane = threadIdx.x & 63;
  const int m0 = blockIdx.y * 128;
  const int n0 = blockIdx.x * 128;
  floatx4 acc[4][4] = {};
  gemm_core_lds(A + (size_t)m0 * Dn, W + (size_t)n0 * Dn, Dn, acc, threadIdx.x, As, Bs);
  const int w = threadIdx.x >> 6;
  const int wm = m0 + (w >> 1) * 64, wn = n0 + (w & 1) * 64;
  const int r = lane & 15, qd = lane >> 4;
#pragma unroll
  for (int i = 0; i < 4; ++i)
#pragma unroll
    for (int j = 0; j < 4; ++j) {
      int col = wn + j * 16 + r;   // d index: h*64+dh
      float bv = bias[col];
#pragma unroll
      for (int rg = 0; rg < 4; ++rg) {
        int row = wm + i * 16 + qd * 4 + rg;   // b*1024 + s
        size_t idx = (((size_t)(row >> 10) * Hn + (col >> 6)) * DHn + (col & 63)) * Sn
                   + (row & 1023);
        vT[idx] = f2bf(acc[i][j][rg] + bv);
      }
    }
}

// ---------------- final GEMM: fp32 output ----------------
__global__ __launch_bounds__(256) void k_gemm_f32out(
    const unsigned short* __restrict__ A, const unsigned short* __restrict__ W,
    const float* __restrict__ bias, float* __restrict__ Cout,
    int M, int N, int K) {
  __shared__ __align__(16) unsigned short As[128 * 64];
  __shared__ __align__(16) unsigned short Bs[128 * 64];
  const int lane = threadIdx.x & 63;
  const int m0 = blockIdx.y * 128;
  const int n0 = blockIdx.x * 128;
  floatx4 acc[4][4] = {};
  gemm_core_lds(A + (size_t)m0 * K, W + (size_t)n0 * K, K, acc, threadIdx.x, As, Bs);
  const int w = threadIdx.x >> 6;
  const int wm = m0 + (w >> 1) * 64, wn = n0 + (w & 1) * 64;
  const int r = lane & 15, qd = lane >> 4;
#pragma unroll
  for (int i = 0; i < 4; ++i)
#pragma unroll
    for (int j = 0; j < 4; ++j) {
      int col = wn + j * 16 + r;
      float bv = bias[col];
#pragma unroll
      for (int rg = 0; rg < 4; ++rg) {
        int row = wm + i * 16 + qd * 4 + rg;
        Cout[(size_t)row * N + col] = acc[i][j][rg] + bv;
      }
    }
}

// ---------------- fused attention: QK -> softmax -> write attn -> combine -> PV
// One block = 16 query rows of one (b,h). 4 waves; wave w owns cols [w*256,w*256+256).
__global__ __launch_bounds__(256) void k_attn_fused(
    const unsigned short* __restrict__ q_bf, const unsigned short* __restrict__ k_bf,
    const int* __restrict__ pad, const float* __restrict__ Cm,
    const float* __restrict__ lam_p, const unsigned short* __restrict__ vT,
    float* __restrict__ attn1, float* __restrict__ attn2, float* __restrict__ ctx) {
  __shared__ __align__(16) unsigned short lds_a[16][1032];  // bf16 attn1 / combined
  __shared__ float smax[4][16];
  __shared__ float ssum[4][16];

  const int bh = blockIdx.y, b = bh >> 4, h = bh & 15;
  const int m0 = blockIdx.x * 16;
  const int lane = threadIdx.x & 63, w = threadIdx.x >> 6;
  const int r = lane & 15, qd = lane >> 4;
  const float lam = *lam_p;

  const unsigned short* qrow = q_bf + ((size_t)(b * Sn + m0 + r)) * D2n + h * DHn;
  const unsigned short* kb   = k_bf + ((size_t)(b * Sn)) * D2n + h * DHn;

  bool msk[16];
#pragma unroll
  for (int j = 0; j < 16; ++j)
    msk[j] = (pad[b * Sn + w * 256 + j * 16 + r] == 0);

  floatx4 acc[16];

  for (int sel = 0; sel < 2; ++sel) {
    short8 a0 = *(const short8*)(qrow + sel * Dn + qd * 8);
    short8 a1 = *(const short8*)(qrow + sel * Dn + 32 + qd * 8);
#pragma unroll
    for (int j = 0; j < 16; ++j) acc[j] = floatx4{0.f, 0.f, 0.f, 0.f};
#pragma unroll
    for (int j = 0; j < 16; ++j) {
      const unsigned short* kp =
          kb + (size_t)(w * 256 + j * 16 + r) * D2n + sel * Dn + qd * 8;
      short8 b0 = *(const short8*)(kp);
      short8 b1 = *(const short8*)(kp + 32);
      acc[j] = mfma16(a0, b0, acc[j]);
      acc[j] = mfma16(a1, b1, acc[j]);
    }
#pragma unroll
    for (int j = 0; j < 16; ++j)
#pragma unroll
      for (int rg = 0; rg < 4; ++rg)
        acc[j][rg] = msk[j] ? -1e9f : acc[j][rg] * 0.125f;

    // row max: rows qd*4+rg; lanes sharing qd share rows (xor over r bits)
    float mx[4];
#pragma unroll
    for (int rg = 0; rg < 4; ++rg) {
      float m = acc[0][rg];
#pragma unroll
      for (int j = 1; j < 16; ++j) m = fmaxf(m, acc[j][rg]);
      m = fmaxf(m, __shfl_xor(m, 1));
      m = fmaxf(m, __shfl_xor(m, 2));
      m = fmaxf(m, __shfl_xor(m, 4));
      m = fmaxf(m, __shfl_xor(m, 8));
      mx[rg] = m;
    }
    if (r == 0)
#pragma unroll
      for (int rg = 0; rg < 4; ++rg) smax[w][qd * 4 + rg] = mx[rg];
    __syncthreads();
#pragma unroll
    for (int rg = 0; rg < 4; ++rg)
      mx[rg] = fmaxf(fmaxf(smax[0][qd * 4 + rg], smax[1][qd * 4 + rg]),
                     fmaxf(smax[2][qd * 4 + rg], smax[3][qd * 4 + rg]));

    float sm[4] = {0.f, 0.f, 0.f, 0.f};
#pragma unroll
    for (int j = 0; j < 16; ++j)
#pragma unroll
      for (int rg = 0; rg < 4; ++rg) {
        float e = __expf(acc[j][rg] - mx[rg]);
        acc[j][rg] = e;
        sm[rg] += e;
      }
#pragma unroll
    for (int rg = 0; rg < 4; ++rg) {
      float s = sm[rg];
      s += __shfl_xor(s, 1);
      s += __shfl_xor(s, 2);
      s += __shfl_xor(s, 4);
      s += __shfl_xor(s, 8);
      sm[rg] = s;
    }
    if (r == 0)
#pragma unroll
      for (int rg = 0; rg < 4; ++rg) ssum[w][qd * 4 + rg] = sm[rg];
    __syncthreads();
    float inv[4];
#pragma unroll
    for (int rg = 0; rg < 4; ++rg)
      inv[rg] = 1.0f / (ssum[0][qd * 4 + rg] + ssum[1][qd * 4 + rg] +
                        ssum[2][qd * 4 + rg] + ssum[3][qd * 4 + rg]);

    float* ao = (sel == 0 ? attn1 : attn2) + (size_t)bh * Sn * Sn;
#pragma unroll
    for (int j = 0; j < 16; ++j)
#pragma unroll
      for (int rg = 0; rg < 4; ++rg) {
        float v = acc[j][rg] * inv[rg];
        acc[j][rg] = v;
        ao[(size_t)(m0 + qd * 4 + rg) * Sn + w * 256 + j * 16 + r] = v;
      }
    if (sel == 0) {
      // stash attn1 (bf16) in LDS; same-lane positions -> wave-ordered, no barrier
#pragma unroll
      for (int j = 0; j < 16; ++j)
#pragma unroll
        for (int rg = 0; rg < 4; ++rg)
          lds_a[qd * 4 + rg][w * 256 + j * 16 + r] = f2bf(acc[j][rg]);
    }
  }

  // combine in place: lds_a <- C .* (attn1 - lam*attn2)   (acc holds attn2)
  const float* cbase = Cm + ((size_t)(b * Sn + m0)) * Sn;
#pragma unroll
  for (int j = 0; j < 16; ++j)
#pragma unroll
    for (int rg = 0; rg < 4; ++rg) {
      int row = qd * 4 + rg, col = w * 256 + j * 16 + r;
      float a1v = bf2f(lds_a[row][col]);
      float cv = cbase[(size_t)row * Sn + col];
      lds_a[row][col] = f2bf(cv * (a1v - lam * acc[j][rg]));
    }
  __syncthreads();

  // PV: wave w accumulates over its k-quarter; cross-wave reduce via LDS
  const unsigned short* vh = vT + (size_t)bh * DHn * Sn;
  floatx4 pv[4] = {};
  for (int k0 = 0; k0 < 256; k0 += 32) {
    short8 af = *(const short8*)(&lds_a[r][w * 256 + k0 + qd * 8]);
#pragma unroll
    for (int j = 0; j < 4; ++j) {
      short8 bf = *(const short8*)(vh + (size_t)(j * 16 + r) * Sn + w * 256 + k0 + qd * 8);
      pv[j] = mfma16(af, bf, pv[j]);
    }
  }
  __syncthreads();  // all PV reads of lds_a done; reuse as reduction buffer
  float* redp = (float*)&lds_a[0][0];  // 4 x 1024 floats = 16 KB (fits in 33 KB)
#pragma unroll
  for (int j = 0; j < 4; ++j)
#pragma unroll
    for (int rg = 0; rg < 4; ++rg)
      redp[w * 1024 + (qd * 4 + rg) * 64 + j * 16 + r] = pv[j][rg];
  __syncthreads();
#pragma unroll
  for (int ii = 0; ii < 4; ++ii) {
    int e = threadIdx.x + ii * 256;
    float s = redp[e] + redp[1024 + e] + redp[2048 + e] + redp[3072 + e];
    int rr = e >> 6, cc = e & 63;
    ctx[((size_t)(b * Sn + m0 + rr)) * Dn + h * DHn + cc] = s;
  }
}

// ---------------- GroupNorm stats: one block per (b,h) group -----------------
__global__ __launch_bounds__(256) void k_gnstats(const float* __restrict__ ctx,
                                                 float* __restrict__ stats) {
  const int g = blockIdx.x, b = g >> 4, h = g & 15;
  const float* p = ctx + (size_t)b * Sn * Dn + h * DHn;
  float s = 0.f, s2 = 0.f;
  for (int idx = threadIdx.x; idx < Sn * DHn; idx += 256) {
    float v = p[(size_t)(idx >> 6) * Dn + (idx & 63)];
    s += v; s2 += v * v;
  }
  s += __shfl_xor(s, 32); s2 += __shfl_xor(s2, 32);
  s += __shfl_xor(s, 16); s2 += __shfl_xor(s2, 16);
  s += __shfl_xor(s, 8);  s2 += __shfl_xor(s2, 8);
  s += __shfl_xor(s, 4);  s2 += __shfl_xor(s2, 4);
  s += __shfl_xor(s, 2);  s2 += __shfl_xor(s2, 2);
  s += __shfl_xor(s, 1);  s2 += __shfl_xor(s2, 1);
  __shared__ float ls[4], ls2[4];
  const int lane = threadIdx.x & 63, w = threadIdx.x >> 6;
  if (lane == 0) { ls[w] = s; ls2[w] = s2; }
  __syncthreads();
  if (threadIdx.x == 0) {
    float S1 = ls[0] + ls[1] + ls[2] + ls[3];
    float S2 = ls2[0] + ls2[1] + ls2[2] + ls2[3];
    float mean = S1 * (1.f / 65536.f);
    float var = S2 * (1.f / 65536.f) - mean * mean;
    stats[g * 2] = mean;
    stats[g * 2 + 1] = rsqrtf(var + 1e-5f);
  }
}

// ---------------- normalize + gn affine + 0.2 scale -> bf16 ------------------
__global__ void k_norm(const float* __restrict__ ctx, const float* __restrict__ stats,
                       const float* __restrict__ gw, const float* __restrict__ gb,
                       unsigned short* __restrict__ outbf) {
  int i = (blockIdx.x * 256 + threadIdx.x) * 4;
  int d = i & (Dn - 1);
  int b = i >> 20;                   // i / (S*D)
  int g = b * Hn + (d >> 6);
  float mean = stats[g * 2], rstd = stats[g * 2 + 1];
  float4 v = *(const float4*)(ctx + i);
  float4 w4 = *(const float4*)(gw + d);
  float4 b4 = *(const float4*)(gb + d);
  ushort4 o;
  o.x = f2bf(((v.x - mean) * rstd * w4.x + b4.x) * 0.2f);
  o.y = f2bf(((v.y - mean) * rstd * w4.y + b4.y) * 0.2f);
  o.z = f2bf(((v.z - mean) * rstd * w4.z + b4.z) * 0.2f);
  o.w = f2bf(((v.w - mean) * rstd * w4.w + b4.w) * 0.2f);
  *(ushort4*)(outbf + i) = o;
}

extern "C" void kernel_launch(void* const* d_in, const int* in_sizes, int n_in,
                              void* d_out, int out_size, void* d_ws, size_t ws_size,
                              hipStream_t stream) {
  (void)in_sizes; (void)n_in; (void)out_size; (void)ws_size;
  const float* x     = (const float*)d_in[0];
  const float* lam   = (const float*)d_in[1];
  const float* Cmask = (const float*)d_in[2];
  const int*   pad   = (const int*)d_in[3];
  const float* wq    = (const float*)d_in[4];
  const float* wq_b  = (const float*)d_in[5];
  const float* wk    = (const float*)d_in[6];
  const float* wk_b  = (const float*)d_in[7];
  const float* wv    = (const float*)d_in[8];
  const float* wv_b  = (const float*)d_in[9];
  const float* ow    = (const float*)d_in[10];
  const float* ow_b  = (const float*)d_in[11];
  const float* gw    = (const float*)d_in[12];
  const float* gb    = (const float*)d_in[13];

  float* outp  = (float*)d_out;                       // [4096,1024]
  float* attn1 = outp + (size_t)BSn * Dn;             // [B,H,S,S]
  float* attn2 = attn1 + (size_t)Bn * Hn * Sn * Sn;

  char* wsb = (char*)d_ws;
  unsigned short* x_bf  = (unsigned short*)(wsb);                       // 8 MiB
  unsigned short* wq_bf = (unsigned short*)(wsb + ((size_t)8  << 20));  // 4 MiB
  unsigned short* wk_bf = (unsigned short*)(wsb + ((size_t)12 << 20));  // 4 MiB
  unsigned short* wv_bf = (unsigned short*)(wsb + ((size_t)16 << 20));  // 2 MiB
  unsigned short* ow_bf = (unsigned short*)(wsb + ((size_t)18 << 20));  // 2 MiB
  unsigned short* q_bf  = (unsigned short*)(wsb + ((size_t)20 << 20));  // 16 MiB
  unsigned short* k_bf  = (unsigned short*)(wsb + ((size_t)36 << 20));  // 16 MiB
  unsigned short* vT    = (unsigned short*)(wsb + ((size_t)52 << 20));  // 8 MiB
  float*          ctx   = (float*)(wsb + ((size_t)60 << 20));           // 16 MiB
  float*          stats = (float*)(wsb + ((size_t)76 << 20));           // 512 B
  unsigned short* sc_bf = x_bf;  // reuse x_bf region after projections

  // bf16 conversions
  k_cvt_bf16<<<4096, 256, 0, stream>>>(x,  x_bf,  BSn * Dn);
  k_cvt_bf16<<<2048, 256, 0, stream>>>(wq, wq_bf, D2n * Dn);
  k_cvt_bf16<<<2048, 256, 0, stream>>>(wk, wk_bf, D2n * Dn);
  k_cvt_bf16<<<1024, 256, 0, stream>>>(wv, wv_bf, Dn * Dn);
  k_cvt_bf16<<<1024, 256, 0, stream>>>(ow, ow_bf, Dn * Dn);

  // projections (LDS-staged MFMA GEMMs)
  k_gemm_bf16out<<<dim3(16, 32), 256, 0, stream>>>(x_bf, wq_bf, wq_b, q_bf,
                                                   BSn, D2n, Dn);
  k_gemm_bf16out<<<dim3(16, 32), 256, 0, stream>>>(x_bf, wk_bf, wk_b, k_bf,
                                                   BSn, D2n, Dn);
  k_gemm_vT<<<dim3(8, 32), 256, 0, stream>>>(x_bf, wv_bf, wv_b, vT);

  // fused attention: scores -> softmax -> attn writes -> combine -> PV -> ctx
  k_attn_fused<<<dim3(Sn / 16, Bn * Hn), 256, 0, stream>>>(
      q_bf, k_bf, pad, Cmask, lam, vT, attn1, attn2, ctx);

  // GroupNorm + scale, then output projection
  k_gnstats<<<Bn * Hn, 256, 0, stream>>>(ctx, stats);
  k_norm<<<4096, 256, 0, stream>>>(ctx, stats, gw, gb, sc_bf);
  k_gemm_f32out<<<dim3(8, 32), 256, 0, stream>>>(sc_bf, ow_bf, ow_b, outp,
                                                 BSn, Dn, Dn);
}

// Round 3
// 937.378 us; speedup vs baseline: 1.2097x; 1.1124x over previous
//
#include <hip/hip_runtime.h>
#include <hip/hip_bf16.h>

#define Bn 4
#define Sn 1024
#define Dn 1024
#define Hn 16
#define DHn 64
#define BSn 4096
#define D2n 2048

typedef __attribute__((ext_vector_type(8))) short short8;
typedef __attribute__((ext_vector_type(8))) __bf16 bf16x8;
typedef __attribute__((ext_vector_type(4))) float floatx4;

static __device__ __forceinline__ unsigned short f2bf(float f) {
  union { float f; unsigned int u; } v; v.f = f;
  unsigned int u = v.u;
  u += 0x7fffu + ((u >> 16) & 1u);
  return (unsigned short)(u >> 16);
}

static __device__ __forceinline__ float bf2f(unsigned short s) {
  union { unsigned int u; float f; } v;
  v.u = ((unsigned int)s) << 16;
  return v.f;
}

static __device__ __forceinline__ floatx4 mfma16(short8 a, short8 b, floatx4 c) {
  return __builtin_amdgcn_mfma_f32_16x16x32_bf16(
      __builtin_bit_cast(bf16x8, a), __builtin_bit_cast(bf16x8, b), c, 0, 0, 0);
}

// ---------------- fused fp32 -> bf16 convert (all 5 arrays, 1 launch) --------
// wq -> wqkv rows [0,2048), wk -> [2048,4096), wv -> [4096,5120)
__global__ void k_cvt_all(const float* __restrict__ x, const float* __restrict__ wq,
                          const float* __restrict__ wk, const float* __restrict__ wv,
                          const float* __restrict__ ow,
                          unsigned short* __restrict__ x_bf,
                          unsigned short* __restrict__ wqkv_bf,
                          unsigned short* __restrict__ ow_bf) {
  const int bid = blockIdx.x;
  const float* src;
  unsigned short* dst;
  int base;
  if (bid < 4096)      { src = x;  dst = x_bf;                            base = bid; }
  else if (bid < 6144) { src = wq; dst = wqkv_bf;                         base = bid - 4096; }
  else if (bid < 8192) { src = wk; dst = wqkv_bf + (size_t)D2n * Dn;      base = bid - 6144; }
  else if (bid < 9216) { src = wv; dst = wqkv_bf + (size_t)2 * D2n * Dn;  base = bid - 8192; }
  else                 { src = ow; dst = ow_bf;                           base = bid - 9216; }
  int i = base * 1024 + threadIdx.x * 4;
  float4 v = *(const float4*)(src + i);
  ushort4 o;
  o.x = f2bf(v.x); o.y = f2bf(v.y); o.z = f2bf(v.z); o.w = f2bf(v.w);
  *(ushort4*)(dst + i) = o;
}

// ---------------- LDS-staged MFMA core (m97 structure) -----------------------
// Block = 256 threads (4 waves), tile 128(M) x 128(N), BK=64.
// Wave w owns the 64x64 sub-tile at (w>>1, w&1). A is [M][K] bf16 row-major,
// W is [N][K] bf16 row-major (computes A @ W^T). Both strides == K.
// LDS: As/Bs [128 rows][64 k] bf16 with XOR 16B-chunk swizzle; swizzle is
// applied on the per-lane GLOBAL source address (LDS dest stays linear) and
// inverted on the ds_read side. Accumulation order over k unchanged.
static __device__ __forceinline__ void gemm_core_lds(
    const unsigned short* __restrict__ A,   // pre-offset: + m0*K
    const unsigned short* __restrict__ W,   // pre-offset: + n0*K
    int K, floatx4 acc[4][4], int tid,
    unsigned short* As, unsigned short* Bs) {
  const int lane = tid & 63, w = tid >> 6;
  const int r = lane & 15, qd = lane >> 4;
  const int srow = lane >> 3;                 // row-within-8-row group, 0..7
  const int scg = (lane & 7) ^ srow;          // swizzled global 16B-chunk idx
  const unsigned short* ag = A + (size_t)(w * 32 + srow) * K + scg * 8;
  const unsigned short* bg = W + (size_t)(w * 32 + srow) * K + scg * 8;
  const int aB = (w >> 1) * 64, bB = (w & 1) * 64;

  for (int k0 = 0; k0 < K; k0 += 64) {
#pragma unroll
    for (int i = 0; i < 4; ++i) {
      __builtin_amdgcn_global_load_lds(
          (const __attribute__((address_space(1))) void*)(ag + (size_t)i * 8 * K + k0),
          (__attribute__((address_space(3))) void*)(As + (w * 4 + i) * 512),
          16, 0, 0);
      __builtin_amdgcn_global_load_lds(
          (const __attribute__((address_space(1))) void*)(bg + (size_t)i * 8 * K + k0),
          (__attribute__((address_space(3))) void*)(Bs + (w * 4 + i) * 512),
          16, 0, 0);
    }
    __syncthreads();
#pragma unroll
    for (int ks = 0; ks < 2; ++ks) {
      short8 a[4], b[4];
#pragma unroll
      for (int i = 0; i < 4; ++i)
        a[i] = *(const short8*)&As[(size_t)(aB + i * 16 + r) * 64 +
                                   (((ks * 4 + qd) ^ (r & 7)) * 8)];
#pragma unroll
      for (int j = 0; j < 4; ++j)
        b[j] = *(const short8*)&Bs[(size_t)(bB + j * 16 + r) * 64 +
                                   (((ks * 4 + qd) ^ (r & 7)) * 8)];
#pragma unroll
      for (int i = 0; i < 4; ++i)
#pragma unroll
        for (int j = 0; j < 4; ++j)
          acc[i][j] = mfma16(a[i], b[j], acc[i][j]);
    }
    __syncthreads();
  }
}

// ---------------- fused q/k/v projection GEMM --------------------------------
// A = x_bf [4096,1024], W = wqkv_bf [5120,1024]. Epilogue routes by n-segment:
// cols [0,2048) -> q_bf, [2048,4096) -> k_bf, [4096,5120) -> vT (transposed).
__global__ __launch_bounds__(256) void k_gemm_qkv(
    const unsigned short* __restrict__ A, const unsigned short* __restrict__ W,
    const float* __restrict__ bq, const float* __restrict__ bk,
    const float* __restrict__ bv,
    unsigned short* __restrict__ q_bf, unsigned short* __restrict__ k_bf,
    unsigned short* __restrict__ vT) {
  __shared__ __align__(16) unsigned short As[128 * 64];
  __shared__ __align__(16) unsigned short Bs[128 * 64];
  const int m0 = blockIdx.y * 128;
  const int n0 = blockIdx.x * 128;
  floatx4 acc[4][4] = {};
  gemm_core_lds(A + (size_t)m0 * Dn, W + (size_t)n0 * Dn, Dn, acc, threadIdx.x, As, Bs);
  const int lane = threadIdx.x & 63, w = threadIdx.x >> 6;
  const int wm = m0 + (w >> 1) * 64, wn = n0 + (w & 1) * 64;
  const int r = lane & 15, qd = lane >> 4;
  if (n0 < 4096) {
    const float* bias = (n0 < D2n) ? bq : bk;
    unsigned short* dst = (n0 < D2n) ? q_bf : k_bf;
    const int cbase = (n0 < D2n) ? 0 : D2n;
#pragma unroll
    for (int i = 0; i < 4; ++i)
#pragma unroll
      for (int j = 0; j < 4; ++j) {
        int col = wn + j * 16 + r - cbase;
        float bvv = bias[col];
#pragma unroll
        for (int rg = 0; rg < 4; ++rg) {
          int row = wm + i * 16 + qd * 4 + rg;
          dst[(size_t)row * D2n + col] = f2bf(acc[i][j][rg] + bvv);
        }
      }
  } else {
#pragma unroll
    for (int i = 0; i < 4; ++i)
#pragma unroll
      for (int j = 0; j < 4; ++j) {
        int d = wn + j * 16 + r - 4096;       // d index: h*64+dh
        float bvv = bv[d];
#pragma unroll
        for (int rg = 0; rg < 4; ++rg) {
          int row = wm + i * 16 + qd * 4 + rg;   // b*1024 + s
          size_t idx = (((size_t)(row >> 10) * Hn + (d >> 6)) * DHn + (d & 63)) * Sn
                     + (row & 1023);
          vT[idx] = f2bf(acc[i][j][rg] + bvv);
        }
      }
  }
}

// ---------------- final GEMM: fp32 output ----------------
__global__ __launch_bounds__(256) void k_gemm_f32out(
    const unsigned short* __restrict__ A, const unsigned short* __restrict__ W,
    const float* __restrict__ bias, float* __restrict__ Cout,
    int M, int N, int K) {
  __shared__ __align__(16) unsigned short As[128 * 64];
  __shared__ __align__(16) unsigned short Bs[128 * 64];
  const int lane = threadIdx.x & 63;
  const int m0 = blockIdx.y * 128;
  const int n0 = blockIdx.x * 128;
  floatx4 acc[4][4] = {};
  gemm_core_lds(A + (size_t)m0 * K, W + (size_t)n0 * K, K, acc, threadIdx.x, As, Bs);
  const int w = threadIdx.x >> 6;
  const int wm = m0 + (w >> 1) * 64, wn = n0 + (w & 1) * 64;
  const int r = lane & 15, qd = lane >> 4;
#pragma unroll
  for (int i = 0; i < 4; ++i)
#pragma unroll
    for (int j = 0; j < 4; ++j) {
      int col = wn + j * 16 + r;
      float bv = bias[col];
#pragma unroll
      for (int rg = 0; rg < 4; ++rg) {
        int row = wm + i * 16 + qd * 4 + rg;
        Cout[(size_t)row * N + col] = acc[i][j][rg] + bv;
      }
    }
}

// ---------------- fused attention: QK -> softmax -> write attn -> combine -> PV
// One block = 16 query rows of one (b,h). 4 waves; wave w owns cols [w*256,w*256+256).
__global__ __launch_bounds__(256) void k_attn_fused(
    const unsigned short* __restrict__ q_bf, const unsigned short* __restrict__ k_bf,
    const int* __restrict__ pad, const float* __restrict__ Cm,
    const float* __restrict__ lam_p, const unsigned short* __restrict__ vT,
    float* __restrict__ attn1, float* __restrict__ attn2, float* __restrict__ ctx) {
  __shared__ __align__(16) unsigned short lds_a[16][1032];  // bf16 attn1 / combined
  __shared__ float smax[4][16];
  __shared__ float ssum[4][16];

  const int bh = blockIdx.y, b = bh >> 4, h = bh & 15;
  const int m0 = blockIdx.x * 16;
  const int lane = threadIdx.x & 63, w = threadIdx.x >> 6;
  const int r = lane & 15, qd = lane >> 4;
  const float lam = *lam_p;

  const unsigned short* qrow = q_bf + ((size_t)(b * Sn + m0 + r)) * D2n + h * DHn;
  const unsigned short* kb   = k_bf + ((size_t)(b * Sn)) * D2n + h * DHn;

  bool msk[16];
#pragma unroll
  for (int j = 0; j < 16; ++j)
    msk[j] = (pad[b * Sn + w * 256 + j * 16 + r] == 0);

  floatx4 acc[16];

  for (int sel = 0; sel < 2; ++sel) {
    short8 a0 = *(const short8*)(qrow + sel * Dn + qd * 8);
    short8 a1 = *(const short8*)(qrow + sel * Dn + 32 + qd * 8);
#pragma unroll
    for (int j = 0; j < 16; ++j) acc[j] = floatx4{0.f, 0.f, 0.f, 0.f};
#pragma unroll
    for (int j = 0; j < 16; ++j) {
      const unsigned short* kp =
          kb + (size_t)(w * 256 + j * 16 + r) * D2n + sel * Dn + qd * 8;
      short8 b0 = *(const short8*)(kp);
      short8 b1 = *(const short8*)(kp + 32);
      acc[j] = mfma16(a0, b0, acc[j]);
      acc[j] = mfma16(a1, b1, acc[j]);
    }
#pragma unroll
    for (int j = 0; j < 16; ++j)
#pragma unroll
      for (int rg = 0; rg < 4; ++rg)
        acc[j][rg] = msk[j] ? -1e9f : acc[j][rg] * 0.125f;

    // row max: rows qd*4+rg; lanes sharing qd share rows (xor over r bits)
    float mx[4];
#pragma unroll
    for (int rg = 0; rg < 4; ++rg) {
      float m = acc[0][rg];
#pragma unroll
      for (int j = 1; j < 16; ++j) m = fmaxf(m, acc[j][rg]);
      m = fmaxf(m, __shfl_xor(m, 1));
      m = fmaxf(m, __shfl_xor(m, 2));
      m = fmaxf(m, __shfl_xor(m, 4));
      m = fmaxf(m, __shfl_xor(m, 8));
      mx[rg] = m;
    }
    if (r == 0)
#pragma unroll
      for (int rg = 0; rg < 4; ++rg) smax[w][qd * 4 + rg] = mx[rg];
    __syncthreads();
#pragma unroll
    for (int rg = 0; rg < 4; ++rg)
      mx[rg] = fmaxf(fmaxf(smax[0][qd * 4 + rg], smax[1][qd * 4 + rg]),
                     fmaxf(smax[2][qd * 4 + rg], smax[3][qd * 4 + rg]));

    float sm[4] = {0.f, 0.f, 0.f, 0.f};
#pragma unroll
    for (int j = 0; j < 16; ++j)
#pragma unroll
      for (int rg = 0; rg < 4; ++rg) {
        float e = __expf(acc[j][rg] - mx[rg]);
        acc[j][rg] = e;
        sm[rg] += e;
      }
#pragma unroll
    for (int rg = 0; rg < 4; ++rg) {
      float s = sm[rg];
      s += __shfl_xor(s, 1);
      s += __shfl_xor(s, 2);
      s += __shfl_xor(s, 4);
      s += __shfl_xor(s, 8);
      sm[rg] = s;
    }
    if (r == 0)
#pragma unroll
      for (int rg = 0; rg < 4; ++rg) ssum[w][qd * 4 + rg] = sm[rg];
    __syncthreads();
    float inv[4];
#pragma unroll
    for (int rg = 0; rg < 4; ++rg)
      inv[rg] = 1.0f / (ssum[0][qd * 4 + rg] + ssum[1][qd * 4 + rg] +
                        ssum[2][qd * 4 + rg] + ssum[3][qd * 4 + rg]);

    float* ao = (sel == 0 ? attn1 : attn2) + (size_t)bh * Sn * Sn;
#pragma unroll
    for (int j = 0; j < 16; ++j)
#pragma unroll
      for (int rg = 0; rg < 4; ++rg) {
        float v = acc[j][rg] * inv[rg];
        acc[j][rg] = v;
        ao[(size_t)(m0 + qd * 4 + rg) * Sn + w * 256 + j * 16 + r] = v;
      }
    if (sel == 0) {
      // stash attn1 (bf16) in LDS; same-lane positions -> wave-ordered, no barrier
#pragma unroll
      for (int j = 0; j < 16; ++j)
#pragma unroll
        for (int rg = 0; rg < 4; ++rg)
          lds_a[qd * 4 + rg][w * 256 + j * 16 + r] = f2bf(acc[j][rg]);
    }
  }

  // combine in place: lds_a <- C .* (attn1 - lam*attn2)   (acc holds attn2)
  const float* cbase = Cm + ((size_t)(b * Sn + m0)) * Sn;
#pragma unroll
  for (int j = 0; j < 16; ++j)
#pragma unroll
    for (int rg = 0; rg < 4; ++rg) {
      int row = qd * 4 + rg, col = w * 256 + j * 16 + r;
      float a1v = bf2f(lds_a[row][col]);
      float cv = cbase[(size_t)row * Sn + col];
      lds_a[row][col] = f2bf(cv * (a1v - lam * acc[j][rg]));
    }
  __syncthreads();

  // PV: wave w accumulates over its k-quarter; cross-wave reduce via LDS
  const unsigned short* vh = vT + (size_t)bh * DHn * Sn;
  floatx4 pv[4] = {};
  for (int k0 = 0; k0 < 256; k0 += 32) {
    short8 af = *(const short8*)(&lds_a[r][w * 256 + k0 + qd * 8]);
#pragma unroll
    for (int j = 0; j < 4; ++j) {
      short8 bf = *(const short8*)(vh + (size_t)(j * 16 + r) * Sn + w * 256 + k0 + qd * 8);
      pv[j] = mfma16(af, bf, pv[j]);
    }
  }
  __syncthreads();  // all PV reads of lds_a done; reuse as reduction buffer
  float* redp = (float*)&lds_a[0][0];  // 4 x 1024 floats = 16 KB
#pragma unroll
  for (int j = 0; j < 4; ++j)
#pragma unroll
    for (int rg = 0; rg < 4; ++rg)
      redp[w * 1024 + (qd * 4 + rg) * 64 + j * 16 + r] = pv[j][rg];
  __syncthreads();
#pragma unroll
  for (int ii = 0; ii < 4; ++ii) {
    int e = threadIdx.x + ii * 256;
    float s = redp[e] + redp[1024 + e] + redp[2048 + e] + redp[3072 + e];
    int rr = e >> 6, cc = e & 63;
    ctx[((size_t)(b * Sn + m0 + rr)) * Dn + h * DHn + cc] = s;
  }
}

// ---------------- GroupNorm partial stats: 256 blocks = (group, quarter) -----
__global__ __launch_bounds__(256) void k_gnstats(const float* __restrict__ ctx,
                                                 float* __restrict__ stats) {
  const int g = blockIdx.x >> 2, qc = blockIdx.x & 3;
  const int b = g >> 4, h = g & 15;
  const float* p = ctx + (size_t)b * Sn * Dn + h * DHn + (size_t)qc * 256 * Dn;
  float s = 0.f, s2 = 0.f;
  for (int idx = threadIdx.x; idx < 256 * DHn; idx += 256) {
    float v = p[(size_t)(idx >> 6) * Dn + (idx & 63)];
    s += v; s2 += v * v;
  }
  s += __shfl_xor(s, 32); s2 += __shfl_xor(s2, 32);
  s += __shfl_xor(s, 16); s2 += __shfl_xor(s2, 16);
  s += __shfl_xor(s, 8);  s2 += __shfl_xor(s2, 8);
  s += __shfl_xor(s, 4);  s2 += __shfl_xor(s2, 4);
  s += __shfl_xor(s, 2);  s2 += __shfl_xor(s2, 2);
  s += __shfl_xor(s, 1);  s2 += __shfl_xor(s2, 1);
  __shared__ float ls[4], ls2[4];
  const int lane = threadIdx.x & 63, w = threadIdx.x >> 6;
  if (lane == 0) { ls[w] = s; ls2[w] = s2; }
  __syncthreads();
  if (threadIdx.x == 0) {
    stats[blockIdx.x * 2]     = ls[0] + ls[1] + ls[2] + ls[3];
    stats[blockIdx.x * 2 + 1] = ls2[0] + ls2[1] + ls2[2] + ls2[3];
  }
}

// ---------------- normalize + gn affine + 0.2 scale -> bf16 ------------------
__global__ void k_norm(const float* __restrict__ ctx, const float* __restrict__ stats,
                       const float* __restrict__ gw, const float* __restrict__ gb,
                       unsigned short* __restrict__ outbf) {
  int i = (blockIdx.x * 256 + threadIdx.x) * 4;
  int d = i & (Dn - 1);
  int b = i >> 20;                   // i / (S*D)
  int g = b * Hn + (d >> 6);
  float S1 = 0.f, S2 = 0.f;
#pragma unroll
  for (int qc = 0; qc < 4; ++qc) {
    S1 += stats[(g * 4 + qc) * 2];
    S2 += stats[(g * 4 + qc) * 2 + 1];
  }
  float mean = S1 * (1.f / 65536.f);
  float rstd = rsqrtf(S2 * (1.f / 65536.f) - mean * mean + 1e-5f);
  float4 v = *(const float4*)(ctx + i);
  float4 w4 = *(const float4*)(gw + d);
  float4 b4 = *(const float4*)(gb + d);
  ushort4 o;
  o.x = f2bf(((v.x - mean) * rstd * w4.x + b4.x) * 0.2f);
  o.y = f2bf(((v.y - mean) * rstd * w4.y + b4.y) * 0.2f);
  o.z = f2bf(((v.z - mean) * rstd * w4.z + b4.z) * 0.2f);
  o.w = f2bf(((v.w - mean) * rstd * w4.w + b4.w) * 0.2f);
  *(ushort4*)(outbf + i) = o;
}

extern "C" void kernel_launch(void* const* d_in, const int* in_sizes, int n_in,
                              void* d_out, int out_size, void* d_ws, size_t ws_size,
                              hipStream_t stream) {
  (void)in_sizes; (void)n_in; (void)out_size; (void)ws_size;
  const float* x     = (const float*)d_in[0];
  const float* lam   = (const float*)d_in[1];
  const float* Cmask = (const float*)d_in[2];
  const int*   pad   = (const int*)d_in[3];
  const float* wq    = (const float*)d_in[4];
  const float* wq_b  = (const float*)d_in[5];
  const float* wk    = (const float*)d_in[6];
  const float* wk_b  = (const float*)d_in[7];
  const float* wv    = (const float*)d_in[8];
  const float* wv_b  = (const float*)d_in[9];
  const float* ow    = (const float*)d_in[10];
  const float* ow_b  = (const float*)d_in[11];
  const float* gw    = (const float*)d_in[12];
  const float* gb    = (const float*)d_in[13];

  float* outp  = (float*)d_out;                       // [4096,1024]
  float* attn1 = outp + (size_t)BSn * Dn;             // [B,H,S,S]
  float* attn2 = attn1 + (size_t)Bn * Hn * Sn * Sn;

  char* wsb = (char*)d_ws;
  unsigned short* x_bf    = (unsigned short*)(wsb);                       // 8 MiB
  unsigned short* wqkv_bf = (unsigned short*)(wsb + ((size_t)8  << 20));  // 10 MiB [5120,1024]
  unsigned short* ow_bf   = (unsigned short*)(wsb + ((size_t)18 << 20));  // 2 MiB
  unsigned short* q_bf    = (unsigned short*)(wsb + ((size_t)20 << 20));  // 16 MiB
  unsigned short* k_bf    = (unsigned short*)(wsb + ((size_t)36 << 20));  // 16 MiB
  unsigned short* vT      = (unsigned short*)(wsb + ((size_t)52 << 20));  // 8 MiB
  float*          ctx     = (float*)(wsb + ((size_t)60 << 20));           // 16 MiB
  float*          stats   = (float*)(wsb + ((size_t)76 << 20));           // 2 KiB
  unsigned short* sc_bf   = x_bf;  // reuse x_bf region after projections

  // all fp32 -> bf16 conversions in one launch
  k_cvt_all<<<10240, 256, 0, stream>>>(x, wq, wk, wv, ow, x_bf, wqkv_bf, ow_bf);

  // fused q/k/v projection GEMM (M=4096, N=5120, K=1024)
  k_gemm_qkv<<<dim3(40, 32), 256, 0, stream>>>(x_bf, wqkv_bf, wq_b, wk_b, wv_b,
                                               q_bf, k_bf, vT);

  // fused attention: scores -> softmax -> attn writes -> combine -> PV -> ctx
  k_attn_fused<<<dim3(Sn / 16, Bn * Hn), 256, 0, stream>>>(
      q_bf, k_bf, pad, Cmask, lam, vT, attn1, attn2, ctx);

  // GroupNorm (partial stats -> fused finalize in norm), then output projection
  k_gnstats<<<256, 256, 0, stream>>>(ctx, stats);
  k_norm<<<4096, 256, 0, stream>>>(ctx, stats, gw, gb, sc_bf);
  k_gemm_f32out<<<dim3(8, 32), 256, 0, stream>>>(sc_bf, ow_bf, ow_b, outp,
                                                 BSn, Dn, Dn);
}